// Round 2
// baseline (312.596 us; speedup 1.0000x reference)
//
#include <hip/hip_runtime.h>

#define SEQ 4096
#define DM 1024
#define DS 64
#define KS 64

#define TCH 64    // channels per block
#define TT  128   // t positions per block
#define R   16    // outputs per thread (along t)

// ---------------------------------------------------------------------------
// Kernel 1: csum[d] = sum_m C[m, d]   (C is [DM, DS] row-major)
// ---------------------------------------------------------------------------
__global__ void csum_kernel(const float* __restrict__ C, float* __restrict__ csum) {
    int d    = threadIdx.x & 63;
    int mloc = threadIdx.x >> 6;
    int m0   = blockIdx.x * 64;
    float s = 0.f;
#pragma unroll
    for (int j = 0; j < 16; ++j)
        s += C[(m0 + j * 4 + mloc) * DS + d];
    __shared__ float red[4][64];
    red[mloc][d] = s;
    __syncthreads();
    if (threadIdx.x < 64) {
        float t = red[0][d] + red[1][d] + red[2][d] + red[3][d];
        atomicAdd(&csum[d], t);
    }
}

// ---------------------------------------------------------------------------
// Kernel 2: Ktl[l*DM + k] = sum_d csum[d] * exp(A[d]*dt[k]*l) * B[d, k]
// [l][k] layout so the conv kernel stages rows coalesced.
// ---------------------------------------------------------------------------
__global__ void taps_kernel(const float* __restrict__ A, const float* __restrict__ B,
                            const float* __restrict__ log_dt,
                            const float* __restrict__ csum, float* __restrict__ Ktl) {
    int g = blockIdx.x * blockDim.x + threadIdx.x;   // 0 .. 65535
    int k = g & (DM - 1);
    int l = g >> 10;                                 // uniform per block
    float dt = __expf(log_dt[k]);
    float fl = (float)l;
    float acc = 0.f;
#pragma unroll 8
    for (int d = 0; d < DS; ++d)
        acc += csum[d] * __expf(A[d] * dt * fl) * B[d * DM + k];
    Ktl[g] = acc;
}

// ---------------------------------------------------------------------------
// Main conv: y[b,t,k] = D[k]*u[b,t,k] + sum_l Ktl[l,k]*u[b,t+31-l,k]
// Block: 256 thr = 4 waves. lane pair-mapping: c2 = tid&31 -> channels
// {k0+2c2, k0+2c2+1} (float2); tg = tid>>5 -> t-range [t0+tg*16, +16).
// Tap loop chunked 4x16 with a sliding 31-wide float2 register window;
// all indices compile-time constants -> SSA-renamed, no scratch.
// ---------------------------------------------------------------------------
template<bool GUARD>
__device__ __forceinline__ float2 ldu(const float2* __restrict__ up2, int t) {
    if (GUARD) {
        if (t >= 0 && t < SEQ) return up2[(size_t)t * (DM / 2)];
        return make_float2(0.f, 0.f);
    }
    return up2[(size_t)t * (DM / 2)];
}

template<bool GUARD>
__device__ __forceinline__ void do_tile(const float2* __restrict__ up2,
                                        float2* __restrict__ yp2,
                                        const float (*tapsL)[66],
                                        float2 D2, int ts, int c2) {
    float2 acc[R];
#pragma unroll
    for (int r = 0; r < R; ++r) acc[r] = make_float2(0.f, 0.f);

    // chunk c covers taps l in [16c, 16c+16); its window is u[ts+16-16c .. ts+46-16c]
    float2 w[31];
#pragma unroll
    for (int i = 0; i < 31; ++i) w[i] = ldu<GUARD>(up2, ts + 16 + i);

#pragma unroll
    for (int c = 0; c < 4; ++c) {
        if (c > 0) {
            // slide window down by 16 t: reuse 15, load 16 new
#pragma unroll
            for (int i = 30; i >= 16; --i) w[i] = w[i - 16];
            int wb = ts + 16 - 16 * c;
#pragma unroll
            for (int i = 0; i < 16; ++i) w[i] = ldu<GUARD>(up2, wb + i);
        }
        if (c == 1) {
            // window now holds u[ts .. ts+30]: fold in the D*u term
#pragma unroll
            for (int r = 0; r < R; ++r) {
                acc[r].x = fmaf(D2.x, w[r].x, acc[r].x);
                acc[r].y = fmaf(D2.y, w[r].y, acc[r].y);
            }
        }
#pragma unroll
        for (int j = 0; j < 16; ++j) {
            float2 t2 = *(const float2*)&tapsL[16 * c + j][2 * c2];
#pragma unroll
            for (int r = 0; r < R; ++r) {
                acc[r].x = fmaf(t2.x, w[r + 15 - j].x, acc[r].x);
                acc[r].y = fmaf(t2.y, w[r + 15 - j].y, acc[r].y);
            }
        }
    }

#pragma unroll
    for (int r = 0; r < R; ++r)
        yp2[(size_t)(ts + r) * (DM / 2)] = acc[r];
}

__global__ __launch_bounds__(256)
void conv_kernel(const float* __restrict__ u, const float* __restrict__ Ktl,
                 const float* __restrict__ D, float* __restrict__ y) {
    __shared__ __align__(16) float tapsL[KS][66];   // +2 pad keeps b64 reads 2-way (free)

    int k0 = blockIdx.x * TCH;
    int t0 = blockIdx.y * TT;
    int b  = blockIdx.z;

    for (int i = threadIdx.x; i < KS * TCH; i += 256) {
        int l = i >> 6, kk = i & 63;
        tapsL[l][kk] = Ktl[l * DM + k0 + kk];
    }
    __syncthreads();

    int c2 = threadIdx.x & 31;
    int tg = threadIdx.x >> 5;
    int ts = t0 + tg * R;
    int p  = (k0 >> 1) + c2;

    const float2* up2 = (const float2*)u + (size_t)b * SEQ * (DM / 2) + p;
    float2*       yp2 = (float2*)y       + (size_t)b * SEQ * (DM / 2) + p;
    float2 D2 = *(const float2*)(D + k0 + 2 * c2);

    // block accesses t in [t0-32, t0+158]
    bool interior = (t0 >= 32) && (t0 + 159 <= SEQ);
    if (interior) do_tile<false>(up2, yp2, tapsL, D2, ts, c2);
    else          do_tile<true >(up2, yp2, tapsL, D2, ts, c2);
}

// ---------------------------------------------------------------------------
extern "C" void kernel_launch(void* const* d_in, const int* in_sizes, int n_in,
                              void* d_out, int out_size, void* d_ws, size_t ws_size,
                              hipStream_t stream) {
    const float* u      = (const float*)d_in[0];
    const float* A      = (const float*)d_in[1];
    const float* Bp     = (const float*)d_in[2];
    const float* Cp     = (const float*)d_in[3];
    const float* Dp     = (const float*)d_in[4];
    const float* log_dt = (const float*)d_in[5];
    float* y = (float*)d_out;

    float* csum = (float*)d_ws;            // 64 floats
    float* Ktl  = csum + 64;               // 65536 floats, [l][k] layout

    hipMemsetAsync(csum, 0, DS * sizeof(float), stream);
    csum_kernel<<<16, 256, 0, stream>>>(Cp, csum);
    taps_kernel<<<(DM * KS) / 256, 256, 0, stream>>>(A, Bp, log_dt, csum, Ktl);

    dim3 grid(DM / TCH, SEQ / TT, 8);
    conv_kernel<<<grid, 256, 0, stream>>>(u, Ktl, Dp, y);
}

// Round 3
// 269.816 us; speedup vs baseline: 1.1586x; 1.1586x over previous
//
#include <hip/hip_runtime.h>

#define SEQ 4096
#define DM 1024
#define DS 64
#define KS 64

#define TCH 64            // channels per block
#define TT  128           // t outputs per block
#define R   16            // outputs per thread
#define NROW (TT + 64)    // 192 staged rows: t in [t0-32, t0+159]

// ---------------------------------------------------------------------------
// async global->LDS helper (16B per lane; LDS dest = wave-uniform base + lane*16)
// ---------------------------------------------------------------------------
typedef const __attribute__((address_space(1))) void* gas_ptr;
typedef __attribute__((address_space(3))) void* las_ptr;
__device__ __forceinline__ void async_cp16(const void* g, void* s) {
    __builtin_amdgcn_global_load_lds((gas_ptr)g, (las_ptr)s, 16, 0, 0);
}

// ---------------------------------------------------------------------------
// Kernel 1: csum[d] = sum_m C[m, d]
// ---------------------------------------------------------------------------
__global__ void csum_kernel(const float* __restrict__ C, float* __restrict__ csum) {
    int d    = threadIdx.x & 63;
    int mloc = threadIdx.x >> 6;
    int m0   = blockIdx.x * 64;
    float s = 0.f;
#pragma unroll
    for (int j = 0; j < 16; ++j)
        s += C[(m0 + j * 4 + mloc) * DS + d];
    __shared__ float red[4][64];
    red[mloc][d] = s;
    __syncthreads();
    if (threadIdx.x < 64) {
        float t = red[0][d] + red[1][d] + red[2][d] + red[3][d];
        atomicAdd(&csum[d], t);
    }
}

// ---------------------------------------------------------------------------
// Kernel 2: Ktl[l*DM + k] = sum_d csum[d] * exp(A[d]*dt[k]*l) * B[d, k]
// ---------------------------------------------------------------------------
__global__ void taps_kernel(const float* __restrict__ A, const float* __restrict__ B,
                            const float* __restrict__ log_dt,
                            const float* __restrict__ csum, float* __restrict__ Ktl) {
    int g = blockIdx.x * blockDim.x + threadIdx.x;
    int k = g & (DM - 1);
    int l = g >> 10;
    float dt = __expf(log_dt[k]);
    float fl = (float)l;
    float acc = 0.f;
#pragma unroll 8
    for (int d = 0; d < DS; ++d)
        acc += csum[d] * __expf(A[d] * dt * fl) * B[d * DM + k];
    Ktl[g] = acc;
}

// ---------------------------------------------------------------------------
// Main conv. LDS-staged u tile + taps; chunked sliding register window.
// y[b,t,k] = D[k]*u[b,t,k] + sum_l Kt[l,k]*u[b,t+31-l,k]
// ---------------------------------------------------------------------------
__global__ __launch_bounds__(256, 2)
void conv_kernel(const float* __restrict__ u, const float* __restrict__ Ktl,
                 const float* __restrict__ D, float* __restrict__ y) {
    __shared__ __align__(16) float smem_u[NROW * TCH];   // 48 KB, row stride 256B
    __shared__ __align__(16) float smem_t[KS * TCH];     // 16 KB, row stride 256B

    int k0 = blockIdx.x * TCH;
    int t0 = blockIdx.y * TT;
    int b  = blockIdx.z;

    int lane = threadIdx.x & 63;
    int wv   = threadIdx.x >> 6;

    const float* gt = u + (size_t)b * SEQ * DM + (size_t)(t0 - 32) * DM + k0; // tile origin (row 0 = t0-32)

    bool interior = (blockIdx.y > 0) && (blockIdx.y + 1 < SEQ / TT);

    // ---- stage taps: 16 KB = 4 iters x 4KB ----
#pragma unroll
    for (int j = 0; j < 4; ++j) {
        int fb = j * 4096 + wv * 1024;          // wave-uniform byte offset
        int f  = fb + lane * 16;
        int l  = f >> 8;
        int c  = (f & 255) >> 2;
        async_cp16(Ktl + l * DM + k0 + c, (char*)smem_t + fb);
    }

    // ---- stage u tile: 48 KB = 12 iters x 4KB ----
    if (interior) {
#pragma unroll
        for (int j = 0; j < 12; ++j) {
            int fb = j * 4096 + wv * 1024;
            int f  = fb + lane * 16;
            int r  = f >> 8;
            int c  = (f & 255) >> 2;
            async_cp16(gt + (size_t)r * DM + c, (char*)smem_u + fb);
        }
    } else {
        // guarded VGPR path, zero-fill OOB rows
#pragma unroll
        for (int j = 0; j < 12; ++j) {
            int f = j * 4096 + threadIdx.x * 16;
            int r = f >> 8;
            int c = (f & 255) >> 2;
            int t = t0 - 32 + r;
            float4 v = make_float4(0.f, 0.f, 0.f, 0.f);
            if (t >= 0 && t < SEQ)
                v = *(const float4*)(gt + (size_t)r * DM + c);
            *(float4*)((char*)smem_u + f) = v;
        }
    }
    __syncthreads();

    // ---- compute ----
    int c2 = threadIdx.x & 31;          // channel-pair lane
    int tg = threadIdx.x >> 5;          // t-group 0..7
    int ts = t0 + tg * R;
    int rb = tg * R;                    // row(ts + d) = rb + 32 + d

    const float2* us = (const float2*)smem_u;   // [row][32]
    const float2* tp = (const float2*)smem_t;   // [l][32]

    float2 acc[R];
#pragma unroll
    for (int r = 0; r < R; ++r) acc[r] = make_float2(0.f, 0.f);

    // chunk c covers taps l in [16c,16c+16); window w[i] = u[ts + 16 - 16c + i]
    float2 w[31];
#pragma unroll
    for (int i = 0; i < 31; ++i) w[i] = us[(rb + 48 + i) * 32 + c2];

    float2 D2 = *(const float2*)(D + k0 + 2 * c2);

#pragma unroll
    for (int c = 0; c < 4; ++c) {
        if (c > 0) {
#pragma unroll
            for (int i = 30; i >= 16; --i) w[i] = w[i - 16];
#pragma unroll
            for (int i = 0; i < 16; ++i) w[i] = us[(rb + 48 - 16 * c + i) * 32 + c2];
        }
        if (c == 1) {   // window holds u[ts .. ts+30]: fold in D*u
#pragma unroll
            for (int r = 0; r < R; ++r) {
                acc[r].x = fmaf(D2.x, w[r].x, acc[r].x);
                acc[r].y = fmaf(D2.y, w[r].y, acc[r].y);
            }
        }
#pragma unroll
        for (int j = 0; j < 16; ++j) {
            float2 t2 = tp[(16 * c + j) * 32 + c2];
#pragma unroll
            for (int r = 0; r < R; ++r) {
                acc[r].x = fmaf(t2.x, w[r + 15 - j].x, acc[r].x);
                acc[r].y = fmaf(t2.y, w[r + 15 - j].y, acc[r].y);
            }
        }
    }

    float2* yp2 = (float2*)y + (size_t)b * SEQ * (DM / 2) + (size_t)ts * (DM / 2) + (k0 >> 1) + c2;
#pragma unroll
    for (int r = 0; r < R; ++r)
        yp2[(size_t)r * (DM / 2)] = acc[r];
}

// ---------------------------------------------------------------------------
extern "C" void kernel_launch(void* const* d_in, const int* in_sizes, int n_in,
                              void* d_out, int out_size, void* d_ws, size_t ws_size,
                              hipStream_t stream) {
    const float* u      = (const float*)d_in[0];
    const float* A      = (const float*)d_in[1];
    const float* Bp     = (const float*)d_in[2];
    const float* Cp     = (const float*)d_in[3];
    const float* Dp     = (const float*)d_in[4];
    const float* log_dt = (const float*)d_in[5];
    float* y = (float*)d_out;

    float* csum = (float*)d_ws;            // 64 floats
    float* Ktl  = csum + 64;               // 65536 floats, [l][k]

    hipMemsetAsync(csum, 0, DS * sizeof(float), stream);
    csum_kernel<<<16, 256, 0, stream>>>(Cp, csum);
    taps_kernel<<<(DM * KS) / 256, 256, 0, stream>>>(A, Bp, log_dt, csum, Ktl);

    dim3 grid(DM / TCH, SEQ / TT, 8);
    conv_kernel<<<grid, 256, 0, stream>>>(u, Ktl, Dp, y);
}